// Round 1
// baseline (3677.740 us; speedup 1.0000x reference)
//
#include <hip/hip_runtime.h>

typedef __attribute__((ext_vector_type(8))) short short8v;
typedef __attribute__((ext_vector_type(4))) float f32x4;
typedef __attribute__((ext_vector_type(4))) float float4v;
typedef unsigned long long u64;
typedef unsigned int u32;

#define NHID 1024
#define NCAT 1024
#define NB   64
#define NT   512
#define RINGQ 16384        // u64 per ring slot (128 KB)
#define SENT32 0xFFFFFFFFu

__device__ __forceinline__ short f2bf(float f) {
  union { float f; unsigned u; } c; c.f = f;
  unsigned r = (c.u + 0x7fffu + ((c.u >> 16) & 1u)) >> 16;
  return (short)r;
}

// agent-scope (MALL-coherent, L2-bypassing) 8B atomic store / load
__device__ __forceinline__ void ast(u64* p, u64 v) {
  __hip_atomic_store(p, v, __ATOMIC_RELAXED, __HIP_MEMORY_SCOPE_AGENT);
}
__device__ __forceinline__ u64 ald(const u64* p) {
  return __hip_atomic_load((u64*)p, __ATOMIC_RELAXED, __HIP_MEMORY_SCOPE_AGENT);
}

__device__ __forceinline__ short8v cvt8(float4v a, float4v b) {
  short8v s;
  s[0]=f2bf(a[0]); s[1]=f2bf(a[1]); s[2]=f2bf(a[2]); s[3]=f2bf(a[3]);
  s[4]=f2bf(b[0]); s[5]=f2bf(b[1]); s[6]=f2bf(b[2]); s[7]=f2bf(b[3]);
  return s;
}

// 256 persistent wgs x 256 threads; wg=(mt,cg) owns h-tile rows mt*16.. x cols cg*16..
// SENTINEL PROTOCOL: ring is pre-memset to 0xFF (bf16 0xFFFF = NaN, unreachable
// since h is always finite). Producers publish h quarters with plain agent-scope
// u64 stores -- NO vmcnt drain, NO flag. Consumers poll the data itself with
// agent-scope u64 loads (L2-bypassing, so no stale-line hazard) until no 32-bit
// half equals 0xFFFFFFFF; at that point the data is already in registers.
// All 4 waves split reduce/epilogue/publish: wave w owns acc component r=w
// (rows quad*4+w) and publishes its 4-row quarter independently.
__global__ __launch_bounds__(256, 1) void gru_kernel(
    const float* __restrict__ h0, const float* __restrict__ Wh, const float* __restrict__ Wz,
    const float* __restrict__ Uh, const float* __restrict__ Uz, const float* __restrict__ bz,
    const float* __restrict__ Wout, const float* __restrict__ x,
    u64* __restrict__ ring, float* __restrict__ out)
{
  extern __shared__ char smem[];
  short8v* ufr = (short8v*)smem;                       // weight B-frags, 128 KB
  float*   red = (float*)(smem + 131072);              // [2 par][4 wv][8 comp][64 lane], 16 KB, conflict-free
  short*   rp  = (short*)(smem + 131072 + 16384);      // 4 waves x 128 B repack

  // one-time agent acquire: invalidate L1/L2 so cross-launch stale weight/x lines die
  __builtin_amdgcn_fence(__ATOMIC_ACQUIRE, "agent");

  const int tid  = threadIdx.x;
  const int lane = tid & 63;
  const int wv   = tid >> 6;
  const int mt   = blockIdx.x >> 6;
  const int cg   = blockIdx.x & 63;
  const int col  = lane & 15;
  const int quad = lane >> 4;
  const int kq   = quad * 8;
  const int jg   = cg * 16 + col;

  // ---- one-time: weight B-fragments into LDS (16 cols x K=2048 x 2 gates) ----
  for (int idx = tid; idx < 64 * 2 * 64; idx += 256) {
    int l  = idx & 63;
    int nt = (idx >> 6) & 1;
    int kb = idx >> 7;
    int j  = cg * 16 + (l & 15);
    int k0 = (kb & 31) * 32 + (l >> 4) * 8;
    const float* M = (kb < 32) ? (nt ? Uh : Uz) : (nt ? Wh : Wz);
    short8v v;
#pragma unroll
    for (int e = 0; e < 8; ++e) v[e] = f2bf(M[j * 1024 + k0 + e]);
    ufr[idx] = v;
  }
  __syncthreads();

  // wave w keeps h-state for rows quad*4+w, col jg
  float hl = h0[(mt * 16 + quad * 4 + wv) * NHID + jg];
  const float bzv = bz[jg];
  const int kb0 = wv * 16;   // wave k-range (kb = 32-K units): wv0,1 = h; wv2,3 = x

  short8v xf[16];
  if (wv >= 2) {             // preload x_0 (fp32 direct, convert in-register)
    const float* xrow = x + ((long)(mt * 16 + col) * NT) * NCAT + (kb0 - 32) * 32 + kq;
#pragma unroll
    for (int i = 0; i < 16; ++i)
      xf[i] = cvt8(*(const float4v*)(xrow + i * 32), *(const float4v*)(xrow + i * 32 + 4));
  }

  for (int t = 0; t < NT; ++t) {
    const int par = t & 1;
    f32x4 pz = {0.f,0.f,0.f,0.f}, ph = {0.f,0.f,0.f,0.f};

    if (wv < 2) {
      short8v f[16];
      if (t > 0) {
        // sentinel-poll the h data itself: 32 u64 per lane = rows mt*16+col, K-half kb0
        const u64* hp = ring + (size_t)t * RINGQ + (mt * 16 + col) * 256 + kb0 * 8 + quad * 2;
        u64 d[32];
        for (;;) {
          bool ok = true;
#pragma unroll
          for (int i = 0; i < 16; ++i) { d[2*i] = ald(hp + i*8); d[2*i+1] = ald(hp + i*8 + 1); }
#pragma unroll
          for (int i = 0; i < 32; ++i)
            ok &= ((u32)d[i] != SENT32) & ((u32)(d[i] >> 32) != SENT32);
          if (__ballot(!ok) == 0ull) break;
          __builtin_amdgcn_s_sleep(1);
        }
#pragma unroll
        for (int i = 0; i < 16; ++i) {
          union { u64 u[2]; short8v v; } un;
          un.u[0] = d[2*i]; un.u[1] = d[2*i+1];
          f[i] = un.v;
        }
      } else {
        const float* hrow = h0 + (mt * 16 + col) * NHID + kb0 * 32 + kq;
#pragma unroll
        for (int i = 0; i < 16; ++i)
          f[i] = cvt8(*(const float4v*)(hrow + i * 32), *(const float4v*)(hrow + i * 32 + 4));
      }
#pragma unroll
      for (int i = 0; i < 16; ++i) {
        int kb = kb0 + i;
        pz = __builtin_amdgcn_mfma_f32_16x16x32_bf16(f[i], ufr[kb * 128 + lane],      pz, 0, 0, 0);
        ph = __builtin_amdgcn_mfma_f32_16x16x32_bf16(f[i], ufr[kb * 128 + 64 + lane], ph, 0, 0, 0);
      }
    } else {
#pragma unroll
      for (int i = 0; i < 16; ++i) {
        int kb = kb0 + i;
        pz = __builtin_amdgcn_mfma_f32_16x16x32_bf16(xf[i], ufr[kb * 128 + lane],      pz, 0, 0, 0);
        ph = __builtin_amdgcn_mfma_f32_16x16x32_bf16(xf[i], ufr[kb * 128 + 64 + lane], ph, 0, 0, 0);
      }
      if (t + 1 < NT) {  // prefetch next x (L2-hot after first pass; off critical path)
        const float* xrow = x + ((long)(mt * 16 + col) * NT + (t + 1)) * NCAT + (kb0 - 32) * 32 + kq;
#pragma unroll
        for (int i = 0; i < 16; ++i)
          xf[i] = cvt8(*(const float4v*)(xrow + i * 32), *(const float4v*)(xrow + i * 32 + 4));
      }
    }

    // all waves store partials, component-major (conflict-free scalar ds ops)
    {
      float* base = red + ((par * 4 + wv) * 8) * 64 + lane;
#pragma unroll
      for (int c = 0; c < 4; ++c) { base[c * 64] = pz[c]; base[(4 + c) * 64] = ph[c]; }
    }
    __syncthreads();

    // all waves: reduce component r=wv, epilogue 1 value/lane, publish own quarter
    {
      float az = 0.f, ah = 0.f;
#pragma unroll
      for (int s = 0; s < 4; ++s) {
        az += red[((par * 4 + s) * 8 + wv) * 64 + lane];
        ah += red[((par * 4 + s) * 8 + 4 + wv) * 64 + lane];
      }
      float z  = 1.f / (1.f + __expf(-(az + bzv)));
      float ht = 2.f / (1.f + __expf(-2.f * ah)) - 1.f;   // tanh, overflow-safe
      float v  = hl + z * (ht - hl);
      hl = v;
      rp[wv * 64 + quad * 16 + col] = f2bf(v);            // [4 q][16 col] per wave
      __asm__ volatile("s_waitcnt lgkmcnt(0)" ::: "memory");   // wave-internal LDS RAW
      if (lane < 16) {
        u64 val = ((const u64*)rp)[wv * 16 + lane];       // row 4*(lane>>2)+wv, cols (lane&3)*4..
        int rowg = mt * 16 + (lane >> 2) * 4 + wv;
        ast(ring + (size_t)(t + 1) * RINGQ + rowg * 256 + cg * 4 + (lane & 3), val);
        // no vmcnt drain, no flag: data visibility IS the signal
      }
    }
  }

  // ---- tail: out = hT @ Wout.T (hT = ring[NT]). K-split 256/wave ----
  {
    const int kb0t = wv * 8;
    const u64* hp = ring + (size_t)NT * RINGQ + (mt * 16 + col) * 256 + kb0t * 8 + quad * 2;
    u64 d[16];
    for (;;) {
      bool ok = true;
#pragma unroll
      for (int i = 0; i < 8; ++i) { d[2*i] = ald(hp + i*8); d[2*i+1] = ald(hp + i*8 + 1); }
#pragma unroll
      for (int i = 0; i < 16; ++i)
        ok &= ((u32)d[i] != SENT32) & ((u32)(d[i] >> 32) != SENT32);
      if (__ballot(!ok) == 0ull) break;
      __builtin_amdgcn_s_sleep(1);
    }
    f32x4 acc = {0.f,0.f,0.f,0.f};
    const float* wrow = Wout + (long)jg * NHID + kb0t * 32 + kq;
#pragma unroll
    for (int kb = 0; kb < 8; ++kb) {
      union { u64 u[2]; short8v v; } un;
      un.u[0] = d[2*kb]; un.u[1] = d[2*kb+1];
      float4v w0 = *(const float4v*)(wrow + kb * 32);
      float4v w1 = *(const float4v*)(wrow + kb * 32 + 4);
      acc = __builtin_amdgcn_mfma_f32_16x16x32_bf16(un.v, cvt8(w0, w1), acc, 0, 0, 0);
    }
    {
      float* base = red + (wv * 8) * 64 + lane;
#pragma unroll
      for (int c = 0; c < 4; ++c) base[c * 64] = acc[c];
    }
    __syncthreads();
    if (wv == 0) {
#pragma unroll
      for (int r = 0; r < 4; ++r) {
        float a = 0.f;
#pragma unroll
        for (int s = 0; s < 4; ++s) a += red[(s * 8 + r) * 64 + lane];
        out[(mt * 16 + quad * 4 + r) * NCAT + jg] = a;
      }
    }
  }
}

extern "C" void kernel_launch(void* const* d_in, const int* in_sizes, int n_in,
                              void* d_out, int out_size, void* d_ws, size_t ws_size,
                              hipStream_t stream) {
  const float* x    = (const float*)d_in[0];
  const float* h0   = (const float*)d_in[1];
  const float* Wh   = (const float*)d_in[2];
  const float* Wz   = (const float*)d_in[3];
  const float* Uh   = (const float*)d_in[5];
  const float* Uz   = (const float*)d_in[6];
  const float* bz   = (const float*)d_in[8];
  const float* Wout = (const float*)d_in[10];

  // workspace: h-ring 513 x 128 KB = 67.2 MB, sentinel-filled each launch
  u64* ring = (u64*)d_ws;
  hipMemsetAsync(ring, 0xFF, (size_t)513 * 131072, stream);

  hipFuncSetAttribute((const void*)gru_kernel,
                      hipFuncAttributeMaxDynamicSharedMemorySize, 147968);
  gru_kernel<<<256, 256, 147968, stream>>>(h0, Wh, Wz, Uh, Uz, bz, Wout, x,
                                           ring, (float*)d_out);
}